// Round 8
// baseline (60.862 us; speedup 1.0000x reference)
//
#include <hip/hip_runtime.h>

#define BB   32
#define HH   512
#define WW   512
#define SH   364
#define SW   280
#define RAD  15
#define NK   96
#define HMN  (SH*SW)          // 101920
#define OMN  (HH*WW)          // 262144

#define TS   32               // k_blur1 heatmap tile
#define K1R  (TS + 2*RAD)     // 62
#define OH   48               // k_blur2_mask output tile rows
#define OW   64               // k_blur2_mask output tile cols
#define NRMX 36               // max w3 rows per tile
#define NCMX 37               // max w3 cols per tile

typedef float f4 __attribute__((ext_vector_type(4)));

// derived keypoint j (0..95) of batch b -> rounded clipped (ix, iy) in heatmap space
__device__ __forceinline__ void point_ij(const float* __restrict__ lm, int b, int j,
                                         int& ix, int& iy) {
    int idx; float s;
    if      (j <  6) { idx = 30 + j;        s = 1.0f; }   // p0
    else if (j < 12) { idx = 30 + (j - 6);  s = 1.5f; }   // p01
    else if (j < 25) { idx =  2 + (j - 12); s = 0.7f; }   // p12
    else if (j < 38) { idx =  2 + (j - 25); s = 0.9f; }   // p13
    else if (j < 51) { idx =  2 + (j - 38); s = 0.5f; }   // p11
    else if (j < 71) { idx = 48 + (j - 51); s = 1.0f; }   // p2
    else if (j < 76) { idx =  6 + (j - 71); s = 1.0f; }   // p3
    else             { idx = 48 + (j - 76); s = 1.3f; }   // p21
    const float scal = 364.0f / 512.0f;   // exact 0.7109375
    float lx = lm[b * 136 + idx * 2 + 0] * scal;
    float ly = lm[b * 136 + idx * 2 + 1] * scal;
    float kx, ky;
    if (s == 1.0f) { kx = lx; ky = ly; }
    else {
        float cx = lm[b * 136 + 30 * 2 + 0] * scal;
        float cy = lm[b * 136 + 30 * 2 + 1] * scal;
        kx = (lx - cx) * s + cx;
        ky = (ly - cy) * s + cy;
    }
    ix = __float2int_rn(fminf(fmaxf(kx, 0.0f), (float)(SW - 1)));
    iy = __float2int_rn(fminf(fmaxf(ky, 0.0f), (float)(SH - 1)));
}

// ---- k_blur1: scatter-in-LDS + blur1(sep) + threshold -> w2 (108 blocks) ----
// 32x32 w2 outputs per block, +-15 halo only: minimal blur1 redundancy.
__global__ __launch_bounds__(256) void k_blur1(const float* __restrict__ lm,
                                               const float* __restrict__ wt,
                                               float* __restrict__ w2) {
    __shared__ float gwl[31];
    __shared__ float hm[K1R][K1R];     // 62x62 heatmap region
    __shared__ float tmp[K1R][TS];     // 62x32 after h-conv
    const int r0 = blockIdx.y * TS, c0 = blockIdx.x * TS;
    const int tid = threadIdx.x;

    // exact normalized 1D profile: gn[j] = W[15][j]/sqrt(W[15][15]) => gn_i*gn_j == W[i][j]
    if (tid < 31) gwl[tid] = wt[15 * 31 + tid] / sqrtf(wt[15 * 31 + 15]);
    for (int i = tid; i < K1R * K1R; i += 256) ((float*)hm)[i] = 0.0f;
    __syncthreads();

    float g[31];
    #pragma unroll
    for (int k = 0; k < 31; ++k) g[k] = gwl[k];

    // scatter the 3072 derived points landing in this block's region
    for (int p = tid; p < BB * NK; p += 256) {
        int b = p / NK, j = p - b * NK;
        int ix, iy;
        point_ij(lm, b, j, ix, iy);
        int ly = iy - (r0 - RAD), lx = ix - (c0 - RAD);
        if (ly >= 0 && ly < K1R && lx >= 0 && lx < K1R) hm[ly][lx] = 1.0f;
    }
    __syncthreads();

    // horizontal pass (zero-pad via LDS zeros outside image)
    for (int i = tid; i < K1R * TS; i += 256) {
        int yy = i / TS, x = i - yy * TS;
        float acc = 0.0f;
        #pragma unroll
        for (int d = 0; d < 31; ++d) acc += g[d] * hm[yy][x + d];
        tmp[yy][x] = acc;
    }
    __syncthreads();

    // vertical pass + threshold -> w2
    for (int i = tid; i < TS * TS; i += 256) {
        int y = i / TS, x = i - y * TS;
        int gy = r0 + y, gx = c0 + x;
        if (gy >= SH || gx >= SW) continue;
        float acc = 0.0f;
        #pragma unroll
        for (int d = 0; d < 31; ++d) acc += g[d] * tmp[y + d][x];
        w2[gy * SW + gx] = (acc > 1e-7f) ? 1.0f : acc;
    }
}

// ---- k_blur2_mask: blur2(sep) + bilinear resize + (1-mask) -> om (88 blocks) ----
__global__ __launch_bounds__(256) void k_blur2_mask(const float* __restrict__ w2,
                                                    const float* __restrict__ wt,
                                                    float* __restrict__ om) {
    __shared__ float gwl[31];
    __shared__ float w2r[NRMX + 2*RAD][NCMX + 2*RAD];   // 66x67 staged w2 region
    __shared__ float tmp[NRMX + 2*RAD][NCMX];           // 66x37 after h-conv
    __shared__ float w3r[NRMX][NCMX];                   // 36x37 blurred region
    const int h0 = blockIdx.y * OH, w0 = blockIdx.x * OW;
    const int hl = min(h0 + OH - 1, HH - 1), wl = min(w0 + OW - 1, WW - 1);
    const int tid = threadIdx.x;
    const float sy = (float)SH / (float)HH;   // 0.7109375
    const float sx = (float)SW / (float)WW;   // 0.546875

    if (tid < 31) gwl[tid] = wt[15 * 31 + tid] / sqrtf(wt[15 * 31 + 15]);

    // w3 rows/cols this tile needs
    float fy0 = fmaxf(((float)h0 + 0.5f) * sy - 0.5f, 0.0f);
    float fyl = fminf(((float)hl + 0.5f) * sy - 0.5f, (float)(SH - 1));
    int rbase = (int)fy0;
    int rend  = min(SH - 1, (int)fyl + 1);
    int NR = rend - rbase + 1;                // <= 36
    float fx0 = fmaxf(((float)w0 + 0.5f) * sx - 0.5f, 0.0f);
    float fxl = fminf(((float)wl + 0.5f) * sx - 0.5f, (float)(SW - 1));
    int cbase = (int)fx0;
    int cend  = min(SW - 1, (int)fxl + 1);
    int NC = cend - cbase + 1;                // <= 37
    int SR = NR + 2 * RAD, SC = NC + 2 * RAD;

    // stage w2 region (zero-pad outside image)
    for (int i = tid; i < SR * SC; i += 256) {
        int y = i / SC, x = i - y * SC;
        int gy = rbase - RAD + y, gx = cbase - RAD + x;
        float v = 0.0f;
        if (gy >= 0 && gy < SH && gx >= 0 && gx < SW) v = w2[gy * SW + gx];
        w2r[y][x] = v;
    }
    __syncthreads();

    float g[31];
    #pragma unroll
    for (int k = 0; k < 31; ++k) g[k] = gwl[k];

    // horizontal pass
    for (int i = tid; i < SR * NC; i += 256) {
        int yy = i / NC, x = i - yy * NC;
        float acc = 0.0f;
        #pragma unroll
        for (int d = 0; d < 31; ++d) acc += g[d] * w2r[yy][x + d];
        tmp[yy][x] = acc;
    }
    __syncthreads();

    // vertical pass
    for (int i = tid; i < NR * NC; i += 256) {
        int y = i / NC, x = i - y * NC;
        float acc = 0.0f;
        #pragma unroll
        for (int d = 0; d < 31; ++d) acc += g[d] * tmp[y + d][x];
        w3r[y][x] = acc;
    }
    __syncthreads();

    // bilinear resize + (1 - v) epilogue
    for (int i = tid; i < OH * OW; i += 256) {
        int dh = i / OW, dw = i - dh * OW;
        int h = h0 + dh, w = w0 + dw;
        if (h >= HH || w >= WW) continue;
        float fy = fminf(fmaxf(((float)h + 0.5f) * sy - 0.5f, 0.0f), (float)(SH - 1));
        float fx = fminf(fmaxf(((float)w + 0.5f) * sx - 0.5f, 0.0f), (float)(SW - 1));
        int y0 = (int)fy, x0 = (int)fx;
        int y1 = min(y0 + 1, SH - 1), x1 = min(x0 + 1, SW - 1);
        float ty = fy - (float)y0, tx = fx - (float)x0;
        int ly0 = y0 - rbase, ly1 = y1 - rbase;
        int lx0 = x0 - cbase, lx1 = x1 - cbase;
        float v00 = w3r[ly0][lx0], v01 = w3r[ly0][lx1];
        float v10 = w3r[ly1][lx0], v11 = w3r[ly1][lx1];
        float v = (1.0f - ty) * ((1.0f - tx) * v00 + tx * v01)
                +         ty  * ((1.0f - tx) * v10 + tx * v11);
        om[h * WW + w] = 1.0f - v;
    }
}

// ---- k_final: flat streaming multiply (round-7 structure) ----
__global__ __launch_bounds__(256) void k_final(const f4* __restrict__ in,
                                               const f4* __restrict__ om,
                                               f4* __restrict__ out) {
    const int base = blockIdx.x * 1024 + threadIdx.x;
    f4 a0 = in[base];
    f4 a1 = in[base + 256];
    f4 a2 = in[base + 512];
    f4 a3 = in[base + 768];
    f4 m0 = om[(base)       & (OMN / 4 - 1)];
    f4 m1 = om[(base + 256) & (OMN / 4 - 1)];
    f4 m2 = om[(base + 512) & (OMN / 4 - 1)];
    f4 m3 = om[(base + 768) & (OMN / 4 - 1)];
    out[base]       = a0 * m0;
    out[base + 256] = a1 * m1;
    out[base + 512] = a2 * m2;
    out[base + 768] = a3 * m3;
}

extern "C" void kernel_launch(void* const* d_in, const int* in_sizes, int n_in,
                              void* d_out, int out_size, void* d_ws, size_t ws_size,
                              hipStream_t stream) {
    const float* face = (const float*)d_in[0];   // (32,3,512,512)
    const float* lm   = (const float*)d_in[1];   // (32,68,2)
    const float* wt   = (const float*)d_in[2];   // (1,1,31,31) gaussian, normalized

    float* ws = (float*)d_ws;
    float* w2 = ws;            // 101920 floats
    float* om = ws + HMN;      // 262144 floats (offset 407680 B, 16B-aligned)

    // scatter + blur1 + threshold: 9x12 tiles of 32x32 (minimal halo redundancy)
    k_blur1<<<dim3((SW + TS - 1) / TS, (SH + TS - 1) / TS), 256, 0, stream>>>(lm, wt, w2);
    // blur2 + bilinear + (1-mask): 8x11 output tiles of 64x48
    k_blur2_mask<<<dim3(WW / OW, (HH + OH - 1) / OH), 256, 0, stream>>>(w2, wt, om);
    // flat streaming multiply: 6144 blocks, 4 f4/thread
    int n4 = out_size / 4;           // 6291456
    k_final<<<n4 / 1024, 256, 0, stream>>>(
        (const f4*)face, (const f4*)om, (f4*)d_out);
}

// Round 9
// 52.553 us; speedup vs baseline: 1.1581x; 1.1581x over previous
//
#include <hip/hip_runtime.h>

#define BB   32
#define HH   512
#define WW   512
#define SH   364
#define SW   280
#define RAD  15
#define NK   96
#define OMN  (HH*WW)          // 262144

#define OH   16               // output tile rows per block
#define OW   32               // output tile cols per block
#define NRM  13               // max w3 rows a tile needs
#define NCM  19               // max w3 cols a tile needs (valid cols 0..18)
#define WRM  (NRM + 2*RAD)    // 43 w2 rows
#define HRM  (NRM + 4*RAD)    // 73 hm rows
// padded col widths (16B-multiple rows for f4 LDS loads)
#define HCP  84               // hm cols: need 82 (48+34), pad to 84
#define WCP  52               // w2/t1 cols: need 49 valid, groups cover 0..51
#define NCP  20               // t2/w3 cols: valid 0..18, col 19 garbage (never read)
#define G1   13               // x4-groups over w2/t1 cols (13*4 = 52)
#define G2   5                // x4-groups over t2/w3 cols (5*4 = 20)

typedef float f4 __attribute__((ext_vector_type(4)));

// derived keypoint j (0..95) of batch b -> rounded clipped (ix, iy) in heatmap space
__device__ __forceinline__ void point_ij(const float* __restrict__ lm, int b, int j,
                                         int& ix, int& iy) {
    int idx; float s;
    if      (j <  6) { idx = 30 + j;        s = 1.0f; }   // p0
    else if (j < 12) { idx = 30 + (j - 6);  s = 1.5f; }   // p01
    else if (j < 25) { idx =  2 + (j - 12); s = 0.7f; }   // p12
    else if (j < 38) { idx =  2 + (j - 25); s = 0.9f; }   // p13
    else if (j < 51) { idx =  2 + (j - 38); s = 0.5f; }   // p11
    else if (j < 71) { idx = 48 + (j - 51); s = 1.0f; }   // p2
    else if (j < 76) { idx =  6 + (j - 71); s = 1.0f; }   // p3
    else             { idx = 48 + (j - 76); s = 1.3f; }   // p21
    const float scal = 364.0f / 512.0f;   // exact 0.7109375
    float lx = lm[b * 136 + idx * 2 + 0] * scal;
    float ly = lm[b * 136 + idx * 2 + 1] * scal;
    float kx, ky;
    if (s == 1.0f) { kx = lx; ky = ly; }
    else {
        float cx = lm[b * 136 + 30 * 2 + 0] * scal;
        float cy = lm[b * 136 + 30 * 2 + 1] * scal;
        kx = (lx - cx) * s + cx;
        ky = (ly - cy) * s + cy;
    }
    ix = __float2int_rn(fminf(fmaxf(kx, 0.0f), (float)(SW - 1)));
    iy = __float2int_rn(fminf(fmaxf(ky, 0.0f), (float)(SH - 1)));
}

// ---- K_mask: whole mask pipeline per output tile, one kernel, 512 blocks ----
// scatter -> blur1(sep) -> threshold -> blur2(sep) -> bilinear -> (1-mask)
// LDS-instruction-optimized: 4 outputs/thread; h-pass via 34-reg window,
// v-pass via 31 aligned ds_read_b128.
__global__ __launch_bounds__(256) void k_mask(const float* __restrict__ lm,
                                              const float* __restrict__ wt,
                                              float* __restrict__ om) {
    __shared__ float gwl[31];
    __shared__ alignas(16) float hmS[HRM][HCP];   // 73x84 binary heatmap region
    __shared__ alignas(16) float t1 [HRM][WCP];   // 73x52 after blur1 h-pass
    __shared__ alignas(16) float w2S[WRM][WCP];   // 43x52 thresholded blur1
    __shared__ alignas(16) float t2 [WRM][NCP];   // 43x20 after blur2 h-pass
    __shared__ alignas(16) float w3S[NRM][NCP];   // 13x20 final blurred region

    const int tid = threadIdx.x;
    const int h0 = blockIdx.y * OH, w0 = blockIdx.x * OW;
    const float sy = (float)SH / (float)HH;   // 0.7109375
    const float sx = (float)SW / (float)WW;   // 0.546875

    // exact normalized 1D profile: gn[j] = W[15][j]/sqrt(W[15][15]) => gn_i*gn_j == W[i][j]
    if (tid < 31) gwl[tid] = wt[15 * 31 + tid] / sqrtf(wt[15 * 31 + 15]);

    // w3 rows/cols this tile needs (monotone coord map, clamped)
    const int hl = h0 + OH - 1, wl = w0 + OW - 1;
    float fy0 = fmaxf(((float)h0 + 0.5f) * sy - 0.5f, 0.0f);
    float fyl = fminf(((float)hl + 0.5f) * sy - 0.5f, (float)(SH - 1));
    int rbase = (int)fy0;
    int rend  = min(SH - 1, (int)fyl + 1);
    float fx0 = fmaxf(((float)w0 + 0.5f) * sx - 0.5f, 0.0f);
    float fxl = fminf(((float)wl + 0.5f) * sx - 0.5f, (float)(SW - 1));
    int cbase = (int)fx0;
    int cend  = min(SW - 1, (int)fxl + 1);
    int NR = rend - rbase + 1;          // <= 13
    int NC = cend - cbase + 1;          // <= 19
    int HR = NR + 4 * RAD, HC = NC + 4 * RAD;   // hm region consumed (<= 73 x 79)

    // zero heatmap region (full padded width -> no garbage anywhere in hmS)
    for (int i = tid; i < HRM * HCP; i += 256) ((float*)hmS)[i] = 0.0f;
    __syncthreads();

    float g[31];
    #pragma unroll
    for (int k = 0; k < 31; ++k) g[k] = gwl[k];

    // scatter all 3072 derived points landing in this block's hm region
    for (int p = tid; p < BB * NK; p += 256) {
        int b = p / NK, j = p - b * NK;
        int ix, iy;
        point_ij(lm, b, j, ix, iy);
        int ly = iy - (rbase - 2 * RAD), lx = ix - (cbase - 2 * RAD);
        if (ly >= 0 && ly < HR && lx >= 0 && lx < HC) hmS[ly][lx] = 1.0f;
    }
    __syncthreads();

    // blur1 horizontal: 4 outputs/thread from a 34-element register window.
    // reads hmS cols <= 48+33 = 81 < 84 (zeroed).
    for (int it = tid; it < HRM * G1; it += 256) {
        int y = it / G1, c0 = (it - y * G1) * 4;
        float r[34];
        #pragma unroll
        for (int k = 0; k < 34; ++k) r[k] = hmS[y][c0 + k];
        #pragma unroll
        for (int q = 0; q < 4; ++q) {
            float acc = 0.0f;
            #pragma unroll
            for (int d = 0; d < 31; ++d) acc += g[d] * r[q + d];
            t1[y][c0 + q] = acc;
        }
    }
    __syncthreads();

    // blur1 vertical + threshold + image-bounds zeroing: f4 loads (b128).
    // t1 cols 49..51 are garbage -> w2S cols 49..51 garbage (never read by
    // valid h2 outputs, which need cols <= 48).
    for (int it = tid; it < WRM * G1; it += 256) {
        int y = it / G1, c0 = (it - y * G1) * 4;
        f4 acc = {0.0f, 0.0f, 0.0f, 0.0f};
        #pragma unroll
        for (int d = 0; d < 31; ++d) {
            f4 v = *(const f4*)&t1[y + d][c0];
            acc += v * g[d];
        }
        int gy = rbase - RAD + y;
        bool rowok = (gy >= 0 && gy < SH);
        #pragma unroll
        for (int q = 0; q < 4; ++q) {
            float v = acc[q];
            v = (v > 1e-7f) ? 1.0f : v;
            int gx = cbase - RAD + c0 + q;
            w2S[y][c0 + q] = (rowok && gx >= 0 && gx < SW) ? v : 0.0f;
        }
    }
    __syncthreads();

    // blur2 horizontal: window method. reads w2S cols <= 16+33 = 49;
    // col 49 pollutes only t2 col 19 (never read).
    for (int it = tid; it < WRM * G2; it += 256) {
        int y = it / G2, c0 = (it - y * G2) * 4;
        float r[34];
        #pragma unroll
        for (int k = 0; k < 34; ++k) r[k] = w2S[y][c0 + k];
        #pragma unroll
        for (int q = 0; q < 4; ++q) {
            float acc = 0.0f;
            #pragma unroll
            for (int d = 0; d < 31; ++d) acc += g[d] * r[q + d];
            t2[y][c0 + q] = acc;
        }
    }
    __syncthreads();

    // blur2 vertical: f4 loads. w3S col 19 garbage (bilinear reads cols <= 18).
    for (int it = tid; it < NRM * G2; it += 256) {
        int y = it / G2, c0 = (it - y * G2) * 4;
        f4 acc = {0.0f, 0.0f, 0.0f, 0.0f};
        #pragma unroll
        for (int d = 0; d < 31; ++d) {
            f4 v = *(const f4*)&t2[y + d][c0];
            acc += v * g[d];
        }
        *(f4*)&w3S[y][c0] = acc;
    }
    __syncthreads();

    // bilinear resize + (1 - v) epilogue
    for (int i = tid; i < OH * OW; i += 256) {
        int dh = i / OW, dw = i - dh * OW;
        int h = h0 + dh, w = w0 + dw;
        float fy = fminf(fmaxf(((float)h + 0.5f) * sy - 0.5f, 0.0f), (float)(SH - 1));
        float fx = fminf(fmaxf(((float)w + 0.5f) * sx - 0.5f, 0.0f), (float)(SW - 1));
        int y0 = (int)fy, x0 = (int)fx;
        int y1 = min(y0 + 1, SH - 1), x1 = min(x0 + 1, SW - 1);
        float ty = fy - (float)y0, tx = fx - (float)x0;
        int ly0 = y0 - rbase, ly1 = y1 - rbase;
        int lx0 = x0 - cbase, lx1 = x1 - cbase;
        float v00 = w3S[ly0][lx0], v01 = w3S[ly0][lx1];
        float v10 = w3S[ly1][lx0], v11 = w3S[ly1][lx1];
        float v = (1.0f - ty) * ((1.0f - tx) * v00 + tx * v01)
                +         ty  * ((1.0f - tx) * v10 + tx * v11);
        om[h * WW + w] = 1.0f - v;
    }
}

// ---- k_final: flat streaming multiply (round-7 structure, best measured) ----
__global__ __launch_bounds__(256) void k_final(const f4* __restrict__ in,
                                               const f4* __restrict__ om,
                                               f4* __restrict__ out) {
    const int base = blockIdx.x * 1024 + threadIdx.x;
    f4 a0 = in[base];
    f4 a1 = in[base + 256];
    f4 a2 = in[base + 512];
    f4 a3 = in[base + 768];
    f4 m0 = om[(base)       & (OMN / 4 - 1)];
    f4 m1 = om[(base + 256) & (OMN / 4 - 1)];
    f4 m2 = om[(base + 512) & (OMN / 4 - 1)];
    f4 m3 = om[(base + 768) & (OMN / 4 - 1)];
    out[base]       = a0 * m0;
    out[base + 256] = a1 * m1;
    out[base + 512] = a2 * m2;
    out[base + 768] = a3 * m3;
}

extern "C" void kernel_launch(void* const* d_in, const int* in_sizes, int n_in,
                              void* d_out, int out_size, void* d_ws, size_t ws_size,
                              hipStream_t stream) {
    const float* face = (const float*)d_in[0];   // (32,3,512,512)
    const float* lm   = (const float*)d_in[1];   // (32,68,2)
    const float* wt   = (const float*)d_in[2];   // (1,1,31,31) gaussian, normalized

    float* om = (float*)d_ws;                    // 262144 floats (1 MB)

    // K_mask: 16x32 grid of 32x16 output tiles = 512 blocks (2/CU)
    k_mask<<<dim3(WW / OW, HH / OH), 256, 0, stream>>>(lm, wt, om);
    // k_final: flat streaming multiply, 6144 blocks, 4 f4/thread
    int n4 = out_size / 4;           // 6291456 = 6144 * 1024
    k_final<<<n4 / 1024, 256, 0, stream>>>(
        (const f4*)face, (const f4*)om, (f4*)d_out);
}

// Round 10
// 52.315 us; speedup vs baseline: 1.1634x; 1.0045x over previous
//
#include <hip/hip_runtime.h>

#define BB   32
#define HH   512
#define WW   512
#define SH   364
#define SW   280
#define RAD  15
#define NK   96
#define OMN  (HH*WW)          // 262144

#define OH   16               // output tile rows per block
#define OW   32               // output tile cols per block
#define NRM  13               // max w3 rows a tile needs
#define NCM  19               // max w3 cols a tile needs (valid cols 0..18)
#define WRM  (NRM + 2*RAD)    // 43 w2 rows
#define HRM  (NRM + 4*RAD)    // 73 hm rows
// padded col widths (16B-multiple rows for f4 LDS loads)
#define HCP  84               // hm cols: need 82 (48+34), pad to 84
#define WCP  52               // w2/t1 cols: need 49 valid, groups cover 0..51
#define NCP  20               // t2/w3 cols: valid 0..18, col 19 garbage (never read)
#define G1   13               // x4-groups over w2/t1 cols (13*4 = 52)
#define G2   5                // x4-groups over t2/w3 cols (5*4 = 20)

typedef float f4 __attribute__((ext_vector_type(4)));

// derived keypoint j (0..95) of batch b -> rounded clipped (ix, iy) in heatmap space
__device__ __forceinline__ void point_ij(const float* __restrict__ lm, int b, int j,
                                         int& ix, int& iy) {
    int idx; float s;
    if      (j <  6) { idx = 30 + j;        s = 1.0f; }   // p0
    else if (j < 12) { idx = 30 + (j - 6);  s = 1.5f; }   // p01
    else if (j < 25) { idx =  2 + (j - 12); s = 0.7f; }   // p12
    else if (j < 38) { idx =  2 + (j - 25); s = 0.9f; }   // p13
    else if (j < 51) { idx =  2 + (j - 38); s = 0.5f; }   // p11
    else if (j < 71) { idx = 48 + (j - 51); s = 1.0f; }   // p2
    else if (j < 76) { idx =  6 + (j - 71); s = 1.0f; }   // p3
    else             { idx = 48 + (j - 76); s = 1.3f; }   // p21
    const float scal = 364.0f / 512.0f;   // exact 0.7109375
    float lx = lm[b * 136 + idx * 2 + 0] * scal;
    float ly = lm[b * 136 + idx * 2 + 1] * scal;
    float kx, ky;
    if (s == 1.0f) { kx = lx; ky = ly; }
    else {
        float cx = lm[b * 136 + 30 * 2 + 0] * scal;
        float cy = lm[b * 136 + 30 * 2 + 1] * scal;
        kx = (lx - cx) * s + cx;
        ky = (ly - cy) * s + cy;
    }
    ix = __float2int_rn(fminf(fmaxf(kx, 0.0f), (float)(SW - 1)));
    iy = __float2int_rn(fminf(fmaxf(ky, 0.0f), (float)(SH - 1)));
}

// ---- K_mask: whole mask pipeline per output tile, one kernel, 512 blocks ----
// (unchanged from round 9 — LDS-instruction-optimized)
__global__ __launch_bounds__(256) void k_mask(const float* __restrict__ lm,
                                              const float* __restrict__ wt,
                                              float* __restrict__ om) {
    __shared__ float gwl[31];
    __shared__ alignas(16) float hmS[HRM][HCP];   // 73x84 binary heatmap region
    __shared__ alignas(16) float t1 [HRM][WCP];   // 73x52 after blur1 h-pass
    __shared__ alignas(16) float w2S[WRM][WCP];   // 43x52 thresholded blur1
    __shared__ alignas(16) float t2 [WRM][NCP];   // 43x20 after blur2 h-pass
    __shared__ alignas(16) float w3S[NRM][NCP];   // 13x20 final blurred region

    const int tid = threadIdx.x;
    const int h0 = blockIdx.y * OH, w0 = blockIdx.x * OW;
    const float sy = (float)SH / (float)HH;   // 0.7109375
    const float sx = (float)SW / (float)WW;   // 0.546875

    // exact normalized 1D profile: gn[j] = W[15][j]/sqrt(W[15][15]) => gn_i*gn_j == W[i][j]
    if (tid < 31) gwl[tid] = wt[15 * 31 + tid] / sqrtf(wt[15 * 31 + 15]);

    // w3 rows/cols this tile needs (monotone coord map, clamped)
    const int hl = h0 + OH - 1, wl = w0 + OW - 1;
    float fy0 = fmaxf(((float)h0 + 0.5f) * sy - 0.5f, 0.0f);
    float fyl = fminf(((float)hl + 0.5f) * sy - 0.5f, (float)(SH - 1));
    int rbase = (int)fy0;
    int rend  = min(SH - 1, (int)fyl + 1);
    float fx0 = fmaxf(((float)w0 + 0.5f) * sx - 0.5f, 0.0f);
    float fxl = fminf(((float)wl + 0.5f) * sx - 0.5f, (float)(SW - 1));
    int cbase = (int)fx0;
    int cend  = min(SW - 1, (int)fxl + 1);
    int NR = rend - rbase + 1;          // <= 13
    int NC = cend - cbase + 1;          // <= 19
    int HR = NR + 4 * RAD, HC = NC + 4 * RAD;   // hm region consumed (<= 73 x 79)

    // zero heatmap region (full padded width -> no garbage anywhere in hmS)
    for (int i = tid; i < HRM * HCP; i += 256) ((float*)hmS)[i] = 0.0f;
    __syncthreads();

    float g[31];
    #pragma unroll
    for (int k = 0; k < 31; ++k) g[k] = gwl[k];

    // scatter all 3072 derived points landing in this block's hm region
    for (int p = tid; p < BB * NK; p += 256) {
        int b = p / NK, j = p - b * NK;
        int ix, iy;
        point_ij(lm, b, j, ix, iy);
        int ly = iy - (rbase - 2 * RAD), lx = ix - (cbase - 2 * RAD);
        if (ly >= 0 && ly < HR && lx >= 0 && lx < HC) hmS[ly][lx] = 1.0f;
    }
    __syncthreads();

    // blur1 horizontal: 4 outputs/thread from a 34-element register window.
    for (int it = tid; it < HRM * G1; it += 256) {
        int y = it / G1, c0 = (it - y * G1) * 4;
        float r[34];
        #pragma unroll
        for (int k = 0; k < 34; ++k) r[k] = hmS[y][c0 + k];
        #pragma unroll
        for (int q = 0; q < 4; ++q) {
            float acc = 0.0f;
            #pragma unroll
            for (int d = 0; d < 31; ++d) acc += g[d] * r[q + d];
            t1[y][c0 + q] = acc;
        }
    }
    __syncthreads();

    // blur1 vertical + threshold + image-bounds zeroing: f4 loads (b128).
    for (int it = tid; it < WRM * G1; it += 256) {
        int y = it / G1, c0 = (it - y * G1) * 4;
        f4 acc = {0.0f, 0.0f, 0.0f, 0.0f};
        #pragma unroll
        for (int d = 0; d < 31; ++d) {
            f4 v = *(const f4*)&t1[y + d][c0];
            acc += v * g[d];
        }
        int gy = rbase - RAD + y;
        bool rowok = (gy >= 0 && gy < SH);
        #pragma unroll
        for (int q = 0; q < 4; ++q) {
            float v = acc[q];
            v = (v > 1e-7f) ? 1.0f : v;
            int gx = cbase - RAD + c0 + q;
            w2S[y][c0 + q] = (rowok && gx >= 0 && gx < SW) ? v : 0.0f;
        }
    }
    __syncthreads();

    // blur2 horizontal: window method.
    for (int it = tid; it < WRM * G2; it += 256) {
        int y = it / G2, c0 = (it - y * G2) * 4;
        float r[34];
        #pragma unroll
        for (int k = 0; k < 34; ++k) r[k] = w2S[y][c0 + k];
        #pragma unroll
        for (int q = 0; q < 4; ++q) {
            float acc = 0.0f;
            #pragma unroll
            for (int d = 0; d < 31; ++d) acc += g[d] * r[q + d];
            t2[y][c0 + q] = acc;
        }
    }
    __syncthreads();

    // blur2 vertical: f4 loads.
    for (int it = tid; it < NRM * G2; it += 256) {
        int y = it / G2, c0 = (it - y * G2) * 4;
        f4 acc = {0.0f, 0.0f, 0.0f, 0.0f};
        #pragma unroll
        for (int d = 0; d < 31; ++d) {
            f4 v = *(const f4*)&t2[y + d][c0];
            acc += v * g[d];
        }
        *(f4*)&w3S[y][c0] = acc;
    }
    __syncthreads();

    // bilinear resize + (1 - v) epilogue
    for (int i = tid; i < OH * OW; i += 256) {
        int dh = i / OW, dw = i - dh * OW;
        int h = h0 + dh, w = w0 + dw;
        float fy = fminf(fmaxf(((float)h + 0.5f) * sy - 0.5f, 0.0f), (float)(SH - 1));
        float fx = fminf(fmaxf(((float)w + 0.5f) * sx - 0.5f, 0.0f), (float)(SW - 1));
        int y0 = (int)fy, x0 = (int)fx;
        int y1 = min(y0 + 1, SH - 1), x1 = min(x0 + 1, SW - 1);
        float ty = fy - (float)y0, tx = fx - (float)x0;
        int ly0 = y0 - rbase, ly1 = y1 - rbase;
        int lx0 = x0 - cbase, lx1 = x1 - cbase;
        float v00 = w3S[ly0][lx0], v01 = w3S[ly0][lx1];
        float v10 = w3S[ly1][lx0], v11 = w3S[ly1][lx1];
        float v = (1.0f - ty) * ((1.0f - tx) * v00 + tx * v01)
                +         ty  * ((1.0f - tx) * v10 + tx * v11);
        om[h * WW + w] = 1.0f - v;
    }
}

// ---- k_final: flat streaming multiply; PLAIN loads (face allocates in L3,
//      stays resident across replays) + NT stores (output bypasses cache
//      allocation, doesn't evict face). Isolated change vs round 9. ----
__global__ __launch_bounds__(256) void k_final(const f4* __restrict__ in,
                                               const f4* __restrict__ om,
                                               f4* __restrict__ out) {
    const int base = blockIdx.x * 1024 + threadIdx.x;
    f4 a0 = in[base];
    f4 a1 = in[base + 256];
    f4 a2 = in[base + 512];
    f4 a3 = in[base + 768];
    f4 m0 = om[(base)       & (OMN / 4 - 1)];
    f4 m1 = om[(base + 256) & (OMN / 4 - 1)];
    f4 m2 = om[(base + 512) & (OMN / 4 - 1)];
    f4 m3 = om[(base + 768) & (OMN / 4 - 1)];
    __builtin_nontemporal_store(a0 * m0, &out[base]);
    __builtin_nontemporal_store(a1 * m1, &out[base + 256]);
    __builtin_nontemporal_store(a2 * m2, &out[base + 512]);
    __builtin_nontemporal_store(a3 * m3, &out[base + 768]);
}

extern "C" void kernel_launch(void* const* d_in, const int* in_sizes, int n_in,
                              void* d_out, int out_size, void* d_ws, size_t ws_size,
                              hipStream_t stream) {
    const float* face = (const float*)d_in[0];   // (32,3,512,512)
    const float* lm   = (const float*)d_in[1];   // (32,68,2)
    const float* wt   = (const float*)d_in[2];   // (1,1,31,31) gaussian, normalized

    float* om = (float*)d_ws;                    // 262144 floats (1 MB)

    // K_mask: 16x32 grid of 32x16 output tiles = 512 blocks (2/CU)
    k_mask<<<dim3(WW / OW, HH / OH), 256, 0, stream>>>(lm, wt, om);
    // k_final: flat streaming multiply, 6144 blocks, 4 f4/thread
    int n4 = out_size / 4;           // 6291456 = 6144 * 1024
    k_final<<<n4 / 1024, 256, 0, stream>>>(
        (const f4*)face, (const f4*)om, (f4*)d_out);
}